// Round 1
// baseline (1984.634 us; speedup 1.0000x reference)
//
#include <hip/hip_runtime.h>

#define DI __device__ __forceinline__

typedef float f32x4 __attribute__((ext_vector_type(4)));
typedef __bf16 bf16x8 __attribute__((ext_vector_type(8)));

static DI f32x4 mfma_bf16(bf16x8 a, bf16x8 b, f32x4 c) {
    return __builtin_amdgcn_mfma_f32_16x16x32_bf16(a, b, c, 0, 0, 0);
}
static DI bf16x8 ldb8(const __bf16* p) { return *(const bf16x8*)p; }
static DI float sigf(float x) { return 1.0f / (1.0f + expf(-x)); }

// B=64, T=32, R=49, LOCAL=1024, QVEC=512, EMB=256, HID=512, VOCAB=10000

// ---------------- conversions + gathers (z-dispatched) ----------------
__global__ void convert_kernel(
    const float* Wv, const float* Wih, const float* Whh,
    const float* bih, const float* bhh, const float* Wu,
    const float* emb, const int* answers,
    __bf16* WVo, __bf16* WGo, float* biasg, __bf16* WUo, __bf16* Yo)
{
    int z = blockIdx.z;
    int stride = gridDim.x * blockDim.x;
    int tid0 = blockIdx.x * blockDim.x + threadIdx.x;
    if (z == 0) {
        // W_vocab [10000,512] -> bf16 padded to 10048 rows (zeros)
        const int N = 10048 * 512;
        for (int i = tid0; i < N; i += stride) {
            int v = i >> 9, h = i & 511;
            WVo[i] = (v < 10000) ? (__bf16)Wv[v * 512 + h] : (__bf16)0.0f;
        }
    } else if (z == 1) {
        // Gate-permuted concat [W_ih | W_hh] -> WG [2048 perm rows, 1280]
        // perm row n <-> original row r = (n&3)*512 + (n>>2)  (gate-major -> unit-major)
        const int N = 2048 * 1280;
        for (int i = tid0; i < N; i += stride) {
            int n = i / 1280, k = i - n * 1280;
            int r = (n & 3) * 512 + (n >> 2);
            float val = (k < 768) ? Wih[r * 768 + k] : Whh[r * 512 + (k - 768)];
            WGo[i] = (__bf16)val;
        }
        for (int n = tid0; n < 2048; n += stride) {
            int r = (n & 3) * 512 + (n >> 2);
            biasg[n] = bih[r] + bhh[r];
        }
    } else if (z == 2) {
        // W_u [512,1536] -> bf16 (column order [a|h] already matches)
        const int N = 512 * 1536;
        for (int i = tid0; i < N; i += stride) WUo[i] = (__bf16)Wu[i];
    } else {
        // y_seq gather: t=0 -> emb[1]; t>=1 -> emb[answers[b, t-1]]   [32,64,256] bf16
        const int N = 32 * 64 * 256;
        for (int i = tid0; i < N; i += stride) {
            int t = i >> 14;
            int b = (i >> 8) & 63;
            int e = i & 255;
            int tok = (t == 0) ? 1 : answers[b * 32 + (t - 1)];
            Yo[i] = (__bf16)emb[tok * 256 + e];
        }
    }
}

// ---------------- init: h0 = q@Wh^T, c0 = q@Wc^T, o0 = g@Wg2o^T + b ----------------
__global__ void init_kernel(
    const float* q, const float* g,
    const float* Wh, const float* Wc, const float* Wg2o, const float* bg2o,
    float* h0f, __bf16* h0b, float* c0f, __bf16* o0b)
{
    int z = blockIdx.z;
    const float* A; const float* B; int K;
    if (z == 0)      { A = q; B = Wh;   K = 512; }
    else if (z == 1) { A = q; B = Wc;   K = 512; }
    else             { A = g; B = Wg2o; K = 2048; }
    int n0 = blockIdx.x * 64, m0 = blockIdx.y * 16;
    __shared__ float As[32][16];
    __shared__ float Bs[32][64];
    int tid = threadIdx.x;
    int n = tid & 63, tyq = tid >> 6;
    float acc[4] = {0.f, 0.f, 0.f, 0.f};
    for (int k0 = 0; k0 < K; k0 += 32) {
        {
            int idx = tid * 2, row = idx >> 5, kk = idx & 31;
            const float* ar = A + (m0 + row) * K + k0 + kk;
            As[kk][row] = ar[0];
            As[kk + 1][row] = ar[1];
        }
        {
            int row = tid >> 2, kk = (tid & 3) * 8;
            const float* br = B + (n0 + row) * K + k0 + kk;
            float4 v0 = *(const float4*)br;
            float4 v1 = *(const float4*)(br + 4);
            Bs[kk + 0][row] = v0.x; Bs[kk + 1][row] = v0.y;
            Bs[kk + 2][row] = v0.z; Bs[kk + 3][row] = v0.w;
            Bs[kk + 4][row] = v1.x; Bs[kk + 5][row] = v1.y;
            Bs[kk + 6][row] = v1.z; Bs[kk + 7][row] = v1.w;
        }
        __syncthreads();
        #pragma unroll
        for (int k = 0; k < 32; k++) {
            float4 a = *(const float4*)&As[k][tyq * 4];
            float b = Bs[k][n];
            acc[0] += a.x * b; acc[1] += a.y * b; acc[2] += a.z * b; acc[3] += a.w * b;
        }
        __syncthreads();
    }
    int ng = n0 + n;
    #pragma unroll
    for (int i = 0; i < 4; i++) {
        int m = m0 + tyq * 4 + i;
        float v = acc[i];
        if (z == 0)      { h0f[m * 512 + ng] = v; h0b[m * 512 + ng] = (__bf16)v; }
        else if (z == 1) { c0f[m * 512 + ng] = v; }
        else             { o0b[m * 512 + ng] = (__bf16)(v + bg2o[ng]); }
    }
}

// ---------------- attn_proj = local @ W_attn^T  [3136,1024]x[512,1024] fp32 ----------------
__global__ void attnproj_kernel(const float* A, const float* B, float* C)
{
    int n0 = blockIdx.x * 64, m0 = blockIdx.y * 64;
    __shared__ float As[16][64];
    __shared__ float Bs[16][64];
    int tid = threadIdx.x;
    int tx = tid & 15, ty = tid >> 4;
    float acc[4][4] = {};
    for (int k0 = 0; k0 < 1024; k0 += 16) {
        int row = tid >> 2, kq = (tid & 3) * 4;
        {
            float4 v = *(const float4*)(A + (m0 + row) * 1024 + k0 + kq);
            As[kq + 0][row] = v.x; As[kq + 1][row] = v.y;
            As[kq + 2][row] = v.z; As[kq + 3][row] = v.w;
        }
        {
            float4 v = *(const float4*)(B + (n0 + row) * 1024 + k0 + kq);
            Bs[kq + 0][row] = v.x; Bs[kq + 1][row] = v.y;
            Bs[kq + 2][row] = v.z; Bs[kq + 3][row] = v.w;
        }
        __syncthreads();
        #pragma unroll
        for (int k = 0; k < 16; k++) {
            float4 a = *(const float4*)&As[k][ty * 4];
            float4 b = *(const float4*)&Bs[k][tx * 4];
            acc[0][0] += a.x*b.x; acc[0][1] += a.x*b.y; acc[0][2] += a.x*b.z; acc[0][3] += a.x*b.w;
            acc[1][0] += a.y*b.x; acc[1][1] += a.y*b.y; acc[1][2] += a.y*b.z; acc[1][3] += a.y*b.w;
            acc[2][0] += a.z*b.x; acc[2][1] += a.z*b.y; acc[2][2] += a.z*b.z; acc[2][3] += a.z*b.w;
            acc[3][0] += a.w*b.x; acc[3][1] += a.w*b.y; acc[3][2] += a.w*b.z; acc[3][3] += a.w*b.w;
        }
        __syncthreads();
    }
    #pragma unroll
    for (int i = 0; i < 4; i++)
        #pragma unroll
        for (int j = 0; j < 4; j++)
            C[(m0 + ty * 4 + i) * 512 + n0 + tx * 4 + j] = acc[i][j];
}

// ---------------- per-step K1: gates MFMA GEMM + LSTM pointwise ----------------
// A = [y_t(256) | o_{t-1}(512) | h_{t-1}(512)] bf16, B = WG (perm) [2048,1280] bf16
__global__ void k1_gates_kernel(
    const __bf16* yt, const __bf16* opv, const __bf16* hpv,
    const float* cpv, const __bf16* Wg, const float* biasg,
    float* hof, __bf16* hob, float* cof)
{
    __shared__ float S[64][65];
    int tid = threadIdx.x;
    int n0 = blockIdx.x * 64;
    int w = tid >> 6, lane = tid & 63;
    int row16 = lane & 15, kg = lane >> 4;
    int m0 = w * 16;
    f32x4 acc[4] = {};
    #pragma unroll
    for (int kt = 0; kt < 40; kt++) {
        int k0 = kt * 32;
        const __bf16* aseg; int ld, koff;
        if (k0 < 256)      { aseg = yt;  ld = 256; koff = k0; }
        else if (k0 < 768) { aseg = opv; ld = 512; koff = k0 - 256; }
        else               { aseg = hpv; ld = 512; koff = k0 - 768; }
        bf16x8 af = ldb8(aseg + (m0 + row16) * ld + koff + kg * 8);
        #pragma unroll
        for (int nt = 0; nt < 4; nt++) {
            bf16x8 bf = ldb8(Wg + (n0 + nt * 16 + row16) * 1280 + k0 + kg * 8);
            acc[nt] = mfma_bf16(af, bf, acc[nt]);
        }
    }
    #pragma unroll
    for (int nt = 0; nt < 4; nt++)
        #pragma unroll
        for (int r = 0; r < 4; r++)
            S[m0 + kg * 4 + r][nt * 16 + row16] = acc[nt][r];
    __syncthreads();
    #pragma unroll
    for (int qq = 0; qq < 4; qq++) {
        int it = qq * 256 + tid;
        int b = it >> 4, jl = it & 15;
        float gi = S[b][jl * 4 + 0] + biasg[n0 + jl * 4 + 0];
        float gf = S[b][jl * 4 + 1] + biasg[n0 + jl * 4 + 1];
        float gg = S[b][jl * 4 + 2] + biasg[n0 + jl * 4 + 2];
        float go = S[b][jl * 4 + 3] + biasg[n0 + jl * 4 + 3];
        int j = (n0 >> 2) + jl;
        float cp = cpv[b * 512 + j];
        float cn = sigf(gf) * cp + sigf(gi) * tanhf(gg);
        float hn = sigf(go) * tanhf(cn);
        cof[b * 512 + j] = cn;
        hof[b * 512 + j] = hn;
        hob[b * 512 + j] = (__bf16)hn;
    }
}

// ---------------- per-step K2a: e = ap.h, softmax, a = att-weighted local ----------------
__global__ void k2a_attn_kernel(
    const float* ap, const float* localf, const float* h, __bf16* a_out)
{
    int b = blockIdx.x;
    int tid = threadIdx.x;
    int wave = tid >> 6, lane = tid & 63;
    __shared__ float e_s[49];
    __shared__ float att_s[49];
    const float* hb = h + b * 512;
    float4 h0 = *(const float4*)(hb + lane * 8);
    float4 h1 = *(const float4*)(hb + lane * 8 + 4);
    for (int r = wave; r < 49; r += 4) {
        const float* apr = ap + (b * 49 + r) * 512 + lane * 8;
        float4 p0 = *(const float4*)apr;
        float4 p1 = *(const float4*)(apr + 4);
        float s = p0.x*h0.x + p0.y*h0.y + p0.z*h0.z + p0.w*h0.w
                + p1.x*h1.x + p1.y*h1.y + p1.z*h1.z + p1.w*h1.w;
        #pragma unroll
        for (int off = 32; off > 0; off >>= 1) s += __shfl_xor(s, off);
        if (lane == 0) e_s[r] = s;
    }
    __syncthreads();
    if (tid < 64) {
        float v = (lane < 49) ? e_s[lane] : -3.0e38f;
        float mx = v;
        #pragma unroll
        for (int off = 32; off > 0; off >>= 1) mx = fmaxf(mx, __shfl_xor(mx, off));
        float ex = (lane < 49) ? expf(v - mx) : 0.0f;
        float sm = ex;
        #pragma unroll
        for (int off = 32; off > 0; off >>= 1) sm += __shfl_xor(sm, off);
        if (lane < 49) att_s[lane] = ex / sm;
    }
    __syncthreads();
    float4 acc = {0.f, 0.f, 0.f, 0.f};
    const float* lb = localf + b * 49 * 1024 + tid * 4;
    for (int r = 0; r < 49; r++) {
        float wgt = att_s[r];
        float4 lf = *(const float4*)(lb + r * 1024);
        acc.x += wgt * lf.x; acc.y += wgt * lf.y;
        acc.z += wgt * lf.z; acc.w += wgt * lf.w;
    }
    __bf16* ao = a_out + b * 1024 + tid * 4;
    ao[0] = (__bf16)acc.x; ao[1] = (__bf16)acc.y;
    ao[2] = (__bf16)acc.z; ao[3] = (__bf16)acc.w;
}

// ---------------- per-step K2b: o = tanh([a|h] @ Wu^T + b_u) (MFMA) ----------------
__global__ void k2b_wu_kernel(
    const __bf16* a_bf, const __bf16* h_bf, const __bf16* Wu,
    const float* bu, __bf16* o_out)
{
    int tid = threadIdx.x;
    int n0 = blockIdx.x * 16;
    int w = tid >> 6, lane = tid & 63;
    int row16 = lane & 15, kg = lane >> 4;
    int m0 = w * 16;
    f32x4 acc = {};
    #pragma unroll
    for (int kt = 0; kt < 48; kt++) {
        int k0 = kt * 32;
        const __bf16* aseg; int ld, koff;
        if (k0 < 1024) { aseg = a_bf; ld = 1024; koff = k0; }
        else           { aseg = h_bf; ld = 512;  koff = k0 - 1024; }
        bf16x8 af = ldb8(aseg + (m0 + row16) * ld + koff + kg * 8);
        bf16x8 bf = ldb8(Wu + (n0 + row16) * 1536 + k0 + kg * 8);
        acc = mfma_bf16(af, bf, acc);
    }
    int n = n0 + row16;
    float bun = bu[n];
    #pragma unroll
    for (int r = 0; r < 4; r++) {
        int m = m0 + kg * 4 + r;
        float v = tanhf(acc[r] + bun);
        o_out[m * 512 + n] = (__bf16)v;
    }
}

// ---------------- vocab: logits = O @ Wv^T + b, [2048,512]x[10048,512] MFMA ----------------
__global__ void vocab_kernel(
    const __bf16* A, const __bf16* Wv, const float* bv, float* out)
{
    int tid = threadIdx.x;
    int wid = blockIdx.x * 4 + (tid >> 6);
    int lane = tid & 63;
    int row16 = lane & 15, kg = lane >> 4;
    int mg = wid / 157;
    int ng = wid - mg * 157;
    int m_base = mg * 64, n_base = ng * 64;
    f32x4 acc[4][4] = {};
    for (int kt = 0; kt < 16; kt++) {
        int koff = kt * 32 + kg * 8;
        bf16x8 af[4], bfr[4];
        #pragma unroll
        for (int i = 0; i < 4; i++)
            af[i] = ldb8(A + (m_base + i * 16 + row16) * 512 + koff);
        #pragma unroll
        for (int j = 0; j < 4; j++)
            bfr[j] = ldb8(Wv + (n_base + j * 16 + row16) * 512 + koff);
        #pragma unroll
        for (int i = 0; i < 4; i++)
            #pragma unroll
            for (int j = 0; j < 4; j++)
                acc[i][j] = mfma_bf16(af[i], bfr[j], acc[i][j]);
    }
    #pragma unroll
    for (int j = 0; j < 4; j++) {
        int n = n_base + j * 16 + row16;
        if (n < 10000) {
            float bvn = bv[n];
            #pragma unroll
            for (int i = 0; i < 4; i++) {
                #pragma unroll
                for (int r = 0; r < 4; r++) {
                    int m = m_base + i * 16 + kg * 4 + r;  // m = t*64 + b
                    int t = m >> 6, b = m & 63;
                    out[(b * 32 + t) * 10000 + n] = acc[i][j][r] + bvn;
                }
            }
        }
    }
}

extern "C" void kernel_launch(void* const* d_in, const int* in_sizes, int n_in,
                              void* d_out, int out_size, void* d_ws, size_t ws_size,
                              hipStream_t stream) {
    (void)in_sizes; (void)n_in; (void)out_size; (void)ws_size;
    const float* localf  = (const float*)d_in[0];
    const float* globalf = (const float*)d_in[1];
    const float* qvec    = (const float*)d_in[2];
    const int*   answers = (const int*)d_in[3];
    const float* emb     = (const float*)d_in[4];
    const float* Wg2o    = (const float*)d_in[5];
    const float* bg2o    = (const float*)d_in[6];
    const float* Wh      = (const float*)d_in[7];
    const float* Wc      = (const float*)d_in[8];
    const float* Wih     = (const float*)d_in[9];
    const float* Whh     = (const float*)d_in[10];
    const float* bih     = (const float*)d_in[11];
    const float* bhh     = (const float*)d_in[12];
    const float* Wattn   = (const float*)d_in[13];
    const float* Wu      = (const float*)d_in[14];
    const float* bu      = (const float*)d_in[15];
    const float* Wvocab  = (const float*)d_in[16];
    const float* bvocab  = (const float*)d_in[17];
    float* out = (float*)d_out;

    char* ws = (char*)d_ws;
    __bf16* WV = (__bf16*)(ws + 0);          // 10048*512 bf16
    __bf16* WG = (__bf16*)(ws + 10289152);   // 2048*1280 bf16 (gate-permuted [W_ih|W_hh])
    __bf16* WU = (__bf16*)(ws + 15532032);   // 512*1536 bf16
    __bf16* Y  = (__bf16*)(ws + 17104896);   // 32*64*256 bf16
    float*  BG = (float*) (ws + 18153472);   // 2048 f32 (b_ih+b_hh, permuted)
    __bf16* OB = (__bf16*)(ws + 18161664);   // 33*64*512 bf16 (o slots 0..32; slot0 = o0)
    float*  HF = (float*) (ws + 20324352);   // 2*64*512 f32 (h ping-pong)
    __bf16* HB = (__bf16*)(ws + 20586496);   // 2*64*512 bf16
    float*  CF = (float*) (ws + 20717568);   // 2*64*512 f32 (c ping-pong)
    float*  AP = (float*) (ws + 20979712);   // 64*49*512 f32 (attn_proj)
    __bf16* AB = (__bf16*)(ws + 27402240);   // 64*1024 bf16 (attended features)

    convert_kernel<<<dim3(1024, 1, 4), 256, 0, stream>>>(
        Wvocab, Wih, Whh, bih, bhh, Wu, emb, answers, WV, WG, BG, WU, Y);
    init_kernel<<<dim3(8, 4, 3), 256, 0, stream>>>(
        qvec, globalf, Wh, Wc, Wg2o, bg2o, HF, HB, CF, OB);
    attnproj_kernel<<<dim3(8, 49), 256, 0, stream>>>(localf, Wattn, AP);

    for (int t = 0; t < 32; t++) {
        const __bf16* yt  = Y + t * 64 * 256;
        const __bf16* opv = OB + t * 64 * 512;            // o_{t-1} (slot t)
        const __bf16* hpb = HB + (t & 1) * 64 * 512;      // h_{t-1}
        const float*  cpv = CF + (t & 1) * 64 * 512;      // c_{t-1}
        float*  hof = HF + ((t + 1) & 1) * 64 * 512;      // h_t
        __bf16* hob = HB + ((t + 1) & 1) * 64 * 512;
        float*  cof = CF + ((t + 1) & 1) * 64 * 512;
        __bf16* oob = OB + (t + 1) * 64 * 512;            // o_t (slot t+1)
        k1_gates_kernel<<<32, 256, 0, stream>>>(yt, opv, hpb, cpv, WG, BG, hof, hob, cof);
        k2a_attn_kernel<<<64, 256, 0, stream>>>(AP, localf, hof, AB);
        k2b_wu_kernel<<<32, 256, 0, stream>>>(AB, hob, WU, bu, oob);
    }
    vocab_kernel<<<1256, 256, 0, stream>>>(OB + 64 * 512, WV, bvocab, out);
}

// Round 2
// 1911.746 us; speedup vs baseline: 1.0381x; 1.0381x over previous
//
#include <hip/hip_runtime.h>

#define DI __device__ __forceinline__

typedef float f32x4 __attribute__((ext_vector_type(4)));
typedef __bf16 bf16x8 __attribute__((ext_vector_type(8)));
typedef __bf16 bf16x4 __attribute__((ext_vector_type(4)));

static DI f32x4 mfma_bf16(bf16x8 a, bf16x8 b, f32x4 c) {
    return __builtin_amdgcn_mfma_f32_16x16x32_bf16(a, b, c, 0, 0, 0);
}
static DI bf16x8 ldb8(const __bf16* p) { return *(const bf16x8*)p; }
static DI float sigf(float x) { return 1.0f / (1.0f + expf(-x)); }

// B=64, T=32, R=49, LOCAL=1024, QVEC=512, EMB=256, HID=512, VOCAB=10000
#define GRID_BLKS 64

// ---------------- grid barrier (cooperative-groups pattern) ----------------
static DI void gbar(unsigned* cnt, unsigned* gen, unsigned tgt) {
    __syncthreads();
    if (threadIdx.x == 0) {
        __threadfence();  // agent-scope release of prior global writes
        unsigned prev = __hip_atomic_fetch_add(cnt, 1u, __ATOMIC_ACQ_REL, __HIP_MEMORY_SCOPE_AGENT);
        if (prev == GRID_BLKS - 1) {
            __hip_atomic_store(cnt, 0u, __ATOMIC_RELAXED, __HIP_MEMORY_SCOPE_AGENT);
            __hip_atomic_fetch_add(gen, 1u, __ATOMIC_RELEASE, __HIP_MEMORY_SCOPE_AGENT);
        } else {
            while (__hip_atomic_load(gen, __ATOMIC_ACQUIRE, __HIP_MEMORY_SCOPE_AGENT) < tgt)
                __builtin_amdgcn_s_sleep(2);
        }
    }
    __syncthreads();
}

// ---------------- conversions + gathers (z-dispatched) ----------------
__global__ void convert_kernel(
    const float* Wv, const float* Wih, const float* Whh,
    const float* bih, const float* bhh, const float* Wu,
    const float* emb, const int* answers, const float* localf,
    __bf16* WVo, __bf16* WGo, float* biasg, __bf16* WUo, __bf16* Yo, __bf16* LFo)
{
    int z = blockIdx.z;
    int stride = gridDim.x * blockDim.x;
    int tid0 = blockIdx.x * blockDim.x + threadIdx.x;
    if (z == 0) {
        // W_vocab [10000,512] -> bf16 padded to 10112 rows (zeros)
        const int N = 10112 * 512;
        for (int i = tid0; i < N; i += stride) {
            int v = i >> 9, h = i & 511;
            WVo[i] = (v < 10000) ? (__bf16)Wv[v * 512 + h] : (__bf16)0.0f;
        }
    } else if (z == 1) {
        // Gate-permuted concat [W_ih | W_hh] -> WG [2048 perm rows, 1280]
        // perm row n <-> original row r = (n&3)*512 + (n>>2)
        const int N = 2048 * 1280;
        for (int i = tid0; i < N; i += stride) {
            int n = i / 1280, k = i - n * 1280;
            int r = (n & 3) * 512 + (n >> 2);
            float val = (k < 768) ? Wih[r * 768 + k] : Whh[r * 512 + (k - 768)];
            WGo[i] = (__bf16)val;
        }
        for (int n = tid0; n < 2048; n += stride) {
            int r = (n & 3) * 512 + (n >> 2);
            biasg[n] = bih[r] + bhh[r];
        }
    } else if (z == 2) {
        const int N = 512 * 1536;
        for (int i = tid0; i < N; i += stride) WUo[i] = (__bf16)Wu[i];
    } else if (z == 3) {
        // y_seq gather: t=0 -> emb[1]; t>=1 -> emb[answers[b, t-1]]   [32,64,256]
        const int N = 32 * 64 * 256;
        for (int i = tid0; i < N; i += stride) {
            int t = i >> 14;
            int b = (i >> 8) & 63;
            int e = i & 255;
            int tok = (t == 0) ? 1 : answers[b * 32 + (t - 1)];
            Yo[i] = (__bf16)emb[tok * 256 + e];
        }
    } else {
        // local features f32 -> bf16
        const int N = 64 * 49 * 1024;
        for (int i = tid0; i < N; i += stride) LFo[i] = (__bf16)localf[i];
    }
}

// ---------------- init: h0 = q@Wh^T, c0 = q@Wc^T, o0 = g@Wg2o^T + b ----------------
__global__ void init_kernel(
    const float* q, const float* g,
    const float* Wh, const float* Wc, const float* Wg2o, const float* bg2o,
    __bf16* h0b, float* c0f, __bf16* o0b)
{
    int z = blockIdx.z;
    const float* A; const float* B; int K;
    if (z == 0)      { A = q; B = Wh;   K = 512; }
    else if (z == 1) { A = q; B = Wc;   K = 512; }
    else             { A = g; B = Wg2o; K = 2048; }
    int n0 = blockIdx.x * 64, m0 = blockIdx.y * 16;
    __shared__ float As[32][16];
    __shared__ float Bs[32][64];
    int tid = threadIdx.x;
    int n = tid & 63, tyq = tid >> 6;
    float acc[4] = {0.f, 0.f, 0.f, 0.f};
    for (int k0 = 0; k0 < K; k0 += 32) {
        {
            int idx = tid * 2, row = idx >> 5, kk = idx & 31;
            const float* ar = A + (m0 + row) * K + k0 + kk;
            As[kk][row] = ar[0];
            As[kk + 1][row] = ar[1];
        }
        {
            int row = tid >> 2, kk = (tid & 3) * 8;
            const float* br = B + (n0 + row) * K + k0 + kk;
            float4 v0 = *(const float4*)br;
            float4 v1 = *(const float4*)(br + 4);
            Bs[kk + 0][row] = v0.x; Bs[kk + 1][row] = v0.y;
            Bs[kk + 2][row] = v0.z; Bs[kk + 3][row] = v0.w;
            Bs[kk + 4][row] = v1.x; Bs[kk + 5][row] = v1.y;
            Bs[kk + 6][row] = v1.z; Bs[kk + 7][row] = v1.w;
        }
        __syncthreads();
        #pragma unroll
        for (int k = 0; k < 32; k++) {
            float4 a = *(const float4*)&As[k][tyq * 4];
            float b = Bs[k][n];
            acc[0] += a.x * b; acc[1] += a.y * b; acc[2] += a.z * b; acc[3] += a.w * b;
        }
        __syncthreads();
    }
    int ng = n0 + n;
    #pragma unroll
    for (int i = 0; i < 4; i++) {
        int m = m0 + tyq * 4 + i;
        float v = acc[i];
        if (z == 0)      { h0b[m * 512 + ng] = (__bf16)v; }
        else if (z == 1) { c0f[m * 512 + ng] = v; }
        else             { o0b[m * 512 + ng] = (__bf16)(v + bg2o[ng]); }
    }
}

// ---------------- attn_proj = localf @ W_attn^T -> bf16 [3136,512], MFMA ----------------
__global__ __launch_bounds__(256) void attnproj_kernel(
    const float* Af, const float* Bf, __bf16* APo)
{
    __shared__ __bf16 As[64][72];
    __shared__ __bf16 Bs[64][72];
    int tid = threadIdx.x;
    int m0 = blockIdx.x * 64, n0 = blockIdx.y * 64;
    int w = tid >> 6, lane = tid & 63, row16 = lane & 15, kg = lane >> 4;
    f32x4 acc[4] = {};
    for (int k0 = 0; k0 < 1024; k0 += 64) {
        int r = tid >> 2, col = (tid & 3) * 16;
        const float* ap = Af + (size_t)(m0 + r) * 1024 + k0 + col;
        const float* bp = Bf + (size_t)(n0 + r) * 1024 + k0 + col;
        bf16x8 va0, va1, vb0, vb1;
        #pragma unroll
        for (int u = 0; u < 8; u++) {
            va0[u] = (__bf16)ap[u]; va1[u] = (__bf16)ap[u + 8];
            vb0[u] = (__bf16)bp[u]; vb1[u] = (__bf16)bp[u + 8];
        }
        *(bf16x8*)&As[r][col] = va0; *(bf16x8*)&As[r][col + 8] = va1;
        *(bf16x8*)&Bs[r][col] = vb0; *(bf16x8*)&Bs[r][col + 8] = vb1;
        __syncthreads();
        #pragma unroll
        for (int kt = 0; kt < 2; kt++) {
            bf16x8 af = *(const bf16x8*)&As[w * 16 + row16][kt * 32 + kg * 8];
            #pragma unroll
            for (int j = 0; j < 4; j++) {
                bf16x8 bfv = *(const bf16x8*)&Bs[j * 16 + row16][kt * 32 + kg * 8];
                acc[j] = mfma_bf16(af, bfv, acc[j]);
            }
        }
        __syncthreads();
    }
    #pragma unroll
    for (int j = 0; j < 4; j++)
        #pragma unroll
        for (int r = 0; r < 4; r++)
            APo[(size_t)(m0 + w * 16 + kg * 4 + r) * 512 + n0 + j * 16 + row16] =
                (__bf16)acc[j][r];
}

// ---------------- persistent step-loop kernel (grid = 64 blocks) ----------------
__global__ __launch_bounds__(256) void loop_kernel(
    const __bf16* Yall, const __bf16* WG, const float* BG,
    const __bf16* WU, const float* bu,
    const __bf16* APb, const __bf16* LFb, const float* localf, int use_lfb,
    __bf16* OB, __bf16* HB, float* CF, __bf16* AB,
    unsigned* bar_cnt, unsigned* bar_gen)
{
    __shared__ float SH[4][64][33];
    __shared__ float esh[64];
    __shared__ float ash[64];
    int tid = threadIdx.x;
    int blk = blockIdx.x;
    int w = tid >> 6, lane = tid & 63, row16 = lane & 15, kg = lane >> 4;
    unsigned bgen = 0;

    for (int t = 0; t < 32; t++) {
        int hprev = t & 1, hcur = (t + 1) & 1;
        // ---- Phase A: gates = [y|o|h] @ WG^T, LSTM pointwise -> h,c ----
        {
            const __bf16* Yt  = Yall + t * 16384;
            const __bf16* OBp = OB + t * 32768;
            const __bf16* HBp = HB + hprev * 32768;
            const float*  CFp = CF + hprev * 32768;
            float*  CFc = CF + hcur * 32768;
            __bf16* HBc = HB + hcur * 32768;
            int n0 = blk * 32;
            f32x4 acc[4][2] = {};
            for (int kt = w * 10; kt < w * 10 + 10; kt++) {
                int k0 = kt * 32;
                const __bf16* aseg; int ld, koff;
                if (k0 < 256)      { aseg = Yt;  ld = 256; koff = k0; }
                else if (k0 < 768) { aseg = OBp; ld = 512; koff = k0 - 256; }
                else               { aseg = HBp; ld = 512; koff = k0 - 768; }
                bf16x8 af[4], bfv[2];
                #pragma unroll
                for (int mt = 0; mt < 4; mt++)
                    af[mt] = ldb8(aseg + (mt * 16 + row16) * ld + koff + kg * 8);
                #pragma unroll
                for (int nt = 0; nt < 2; nt++)
                    bfv[nt] = ldb8(WG + (size_t)(n0 + nt * 16 + row16) * 1280 + k0 + kg * 8);
                #pragma unroll
                for (int mt = 0; mt < 4; mt++)
                    #pragma unroll
                    for (int nt = 0; nt < 2; nt++)
                        acc[mt][nt] = mfma_bf16(af[mt], bfv[nt], acc[mt][nt]);
            }
            #pragma unroll
            for (int mt = 0; mt < 4; mt++)
                #pragma unroll
                for (int nt = 0; nt < 2; nt++)
                    #pragma unroll
                    for (int r = 0; r < 4; r++)
                        SH[w][mt * 16 + kg * 4 + r][nt * 16 + row16] = acc[mt][nt][r];
            __syncthreads();
            #pragma unroll
            for (int q = 0; q < 2; q++) {
                int idx = q * 256 + tid;
                int bb = idx >> 3, ul = idx & 7;
                float gv[4];
                #pragma unroll
                for (int g = 0; g < 4; g++) {
                    int col = ul * 4 + g;
                    gv[g] = SH[0][bb][col] + SH[1][bb][col] + SH[2][bb][col] + SH[3][bb][col]
                          + BG[n0 + col];
                }
                int j = blk * 8 + ul;
                float cp = CFp[bb * 512 + j];
                float cn = sigf(gv[1]) * cp + sigf(gv[0]) * tanhf(gv[2]);
                float hn = sigf(gv[3]) * tanhf(cn);
                CFc[bb * 512 + j] = cn;
                HBc[bb * 512 + j] = (__bf16)hn;
            }
        }
        gbar(bar_cnt, bar_gen, ++bgen);

        // ---- Phase B: attention (block = batch) -> a (bf16) ----
        {
            int b = blk;
            const __bf16* hb = HB + ((t + 1) & 1) * 32768 + b * 512;
            for (int r = w; r < 49; r += 4) {
                bf16x8 ap8 = ldb8(APb + (size_t)(b * 49 + r) * 512 + lane * 8);
                bf16x8 h8  = ldb8(hb + lane * 8);
                float s = 0.f;
                #pragma unroll
                for (int u = 0; u < 8; u++) s += (float)ap8[u] * (float)h8[u];
                #pragma unroll
                for (int off = 32; off > 0; off >>= 1) s += __shfl_xor(s, off);
                if (lane == 0) esh[r] = s;
            }
            __syncthreads();
            if (tid < 64) {
                float v = (tid < 49) ? esh[tid] : -3.0e38f;
                float mx = v;
                #pragma unroll
                for (int off = 32; off > 0; off >>= 1) mx = fmaxf(mx, __shfl_xor(mx, off));
                float ex = (tid < 49) ? expf(v - mx) : 0.0f;
                float sm = ex;
                #pragma unroll
                for (int off = 32; off > 0; off >>= 1) sm += __shfl_xor(sm, off);
                if (tid < 49) ash[tid] = ex / sm;
            }
            __syncthreads();
            float a0 = 0.f, a1 = 0.f, a2 = 0.f, a3 = 0.f;
            if (use_lfb) {
                const __bf16* lb = LFb + (size_t)b * 49 * 1024 + tid * 4;
                for (int r = 0; r < 49; r++) {
                    float wt = ash[r];
                    bf16x4 lf = *(const bf16x4*)(lb + r * 1024);
                    a0 += wt * (float)lf[0]; a1 += wt * (float)lf[1];
                    a2 += wt * (float)lf[2]; a3 += wt * (float)lf[3];
                }
            } else {
                const float* lb = localf + (size_t)b * 49 * 1024 + tid * 4;
                for (int r = 0; r < 49; r++) {
                    float wt = ash[r];
                    float4 lf = *(const float4*)(lb + r * 1024);
                    a0 += wt * lf.x; a1 += wt * lf.y; a2 += wt * lf.z; a3 += wt * lf.w;
                }
            }
            __bf16* ao = AB + b * 1024 + tid * 4;
            ao[0] = (__bf16)a0; ao[1] = (__bf16)a1; ao[2] = (__bf16)a2; ao[3] = (__bf16)a3;
        }
        gbar(bar_cnt, bar_gen, ++bgen);

        // ---- Phase C: o = tanh([a|h] @ Wu^T + b_u) ----
        if (blk < 32) {
            int tile = blk * 4 + w;         // 0..127
            int mt = tile & 3;
            int n0c = (tile >> 2) * 16;
            const __bf16* HBc = HB + ((t + 1) & 1) * 32768;
            f32x4 acc = {};
            for (int kt = 0; kt < 48; kt++) {
                int k0 = kt * 32;
                bf16x8 af;
                if (k0 < 1024) af = ldb8(AB + (mt * 16 + row16) * 1024 + k0 + kg * 8);
                else           af = ldb8(HBc + (mt * 16 + row16) * 512 + (k0 - 1024) + kg * 8);
                bf16x8 bfv = ldb8(WU + (size_t)(n0c + row16) * 1536 + k0 + kg * 8);
                acc = mfma_bf16(af, bfv, acc);
            }
            int n = n0c + row16;
            float bun = bu[n];
            __bf16* Oo = OB + (t + 1) * 32768;
            #pragma unroll
            for (int r = 0; r < 4; r++) {
                int m = mt * 16 + kg * 4 + r;
                Oo[m * 512 + n] = (__bf16)tanhf(acc[r] + bun);
            }
        }
        gbar(bar_cnt, bar_gen, ++bgen);
    }
}

// ---------------- vocab: logits = O @ Wv^T + b, 128x128 LDS-tiled MFMA ----------------
__global__ __launch_bounds__(256) void vocab_kernel(
    const __bf16* A, const __bf16* Wv, const float* bv, float* out)
{
    __shared__ __bf16 As[128][72];
    __shared__ __bf16 Bs[128][72];
    int tid = threadIdx.x;
    int m0 = blockIdx.x * 128;   // 16 mblk (fast) for B-tile L2 reuse
    int n0 = blockIdx.y * 128;   // 79 nblk
    int w = tid >> 6, lane = tid & 63, row16 = lane & 15, kg = lane >> 4;
    int mw = (w & 1) * 64, nw = (w >> 1) * 64;
    f32x4 acc[4][4] = {};
    for (int k0 = 0; k0 < 512; k0 += 64) {
        #pragma unroll
        for (int q = 0; q < 2; q++) {
            int c = q * 256 + tid;
            int r = c >> 2, col = (c & 3) * 16;
            bf16x8 v0 = ldb8(A + (size_t)(m0 + r) * 512 + k0 + col);
            bf16x8 v1 = ldb8(A + (size_t)(m0 + r) * 512 + k0 + col + 8);
            *(bf16x8*)&As[r][col] = v0;
            *(bf16x8*)&As[r][col + 8] = v1;
            bf16x8 u0 = ldb8(Wv + (size_t)(n0 + r) * 512 + k0 + col);
            bf16x8 u1 = ldb8(Wv + (size_t)(n0 + r) * 512 + k0 + col + 8);
            *(bf16x8*)&Bs[r][col] = u0;
            *(bf16x8*)&Bs[r][col + 8] = u1;
        }
        __syncthreads();
        #pragma unroll
        for (int kt = 0; kt < 2; kt++) {
            bf16x8 af[4], bfr[4];
            #pragma unroll
            for (int i = 0; i < 4; i++)
                af[i] = *(const bf16x8*)&As[mw + i * 16 + row16][kt * 32 + kg * 8];
            #pragma unroll
            for (int j = 0; j < 4; j++)
                bfr[j] = *(const bf16x8*)&Bs[nw + j * 16 + row16][kt * 32 + kg * 8];
            #pragma unroll
            for (int i = 0; i < 4; i++)
                #pragma unroll
                for (int j = 0; j < 4; j++)
                    acc[i][j] = mfma_bf16(af[i], bfr[j], acc[i][j]);
        }
        __syncthreads();
    }
    #pragma unroll
    for (int j = 0; j < 4; j++) {
        int n = n0 + nw + j * 16 + row16;
        if (n < 10000) {
            float bvn = bv[n];
            #pragma unroll
            for (int i = 0; i < 4; i++) {
                #pragma unroll
                for (int r = 0; r < 4; r++) {
                    int m = m0 + mw + i * 16 + kg * 4 + r;   // m = t*64 + b
                    int tt = m >> 6, b = m & 63;
                    out[(size_t)(b * 32 + tt) * 10000 + n] = acc[i][j][r] + bvn;
                }
            }
        }
    }
}

extern "C" void kernel_launch(void* const* d_in, const int* in_sizes, int n_in,
                              void* d_out, int out_size, void* d_ws, size_t ws_size,
                              hipStream_t stream) {
    (void)in_sizes; (void)n_in; (void)out_size;
    const float* localf  = (const float*)d_in[0];
    const float* globalf = (const float*)d_in[1];
    const float* qvec    = (const float*)d_in[2];
    const int*   answers = (const int*)d_in[3];
    const float* emb     = (const float*)d_in[4];
    const float* Wg2o    = (const float*)d_in[5];
    const float* bg2o    = (const float*)d_in[6];
    const float* Wh      = (const float*)d_in[7];
    const float* Wc      = (const float*)d_in[8];
    const float* Wih     = (const float*)d_in[9];
    const float* Whh     = (const float*)d_in[10];
    const float* bih     = (const float*)d_in[11];
    const float* bhh     = (const float*)d_in[12];
    const float* Wattn   = (const float*)d_in[13];
    const float* Wu      = (const float*)d_in[14];
    const float* bu      = (const float*)d_in[15];
    const float* Wvocab  = (const float*)d_in[16];
    const float* bvocab  = (const float*)d_in[17];
    float* out = (float*)d_out;

    char* ws = (char*)d_ws;
    __bf16* WV  = (__bf16*)(ws + 0);          // 10112*512 bf16 (zero-padded rows)
    __bf16* WG  = (__bf16*)(ws + 10354688);   // 2048*1280 bf16 (gate-permuted [W_ih|W_hh])
    __bf16* WU  = (__bf16*)(ws + 15597568);   // 512*1536 bf16
    __bf16* Y   = (__bf16*)(ws + 17170432);   // 32*64*256 bf16
    float*  BG  = (float*) (ws + 18219008);   // 2048 f32 (b_ih+b_hh, permuted)
    __bf16* OB  = (__bf16*)(ws + 18227200);   // 33*64*512 bf16 (o slots; slot0 = o0)
    __bf16* HB  = (__bf16*)(ws + 20389888);   // 2*64*512 bf16 (h ping-pong)
    float*  CF  = (float*) (ws + 20520960);   // 2*64*512 f32 (c ping-pong)
    __bf16* APb = (__bf16*)(ws + 20783104);   // 64*49*512 bf16 (attn_proj)
    __bf16* AB  = (__bf16*)(ws + 23994368);   // 64*1024 bf16 (attended features)
    unsigned* BAR = (unsigned*)(ws + 24125440); // 256 B barrier state
    __bf16* LFb = (__bf16*)(ws + 24125696);   // 64*49*1024 bf16 (optional, needs 30.6MB ws)
    int use_lfb = (ws_size >= (size_t)30548224) ? 1 : 0;

    hipMemsetAsync(BAR, 0, 256, stream);
    convert_kernel<<<dim3(1024, 1, use_lfb ? 5 : 4), 256, 0, stream>>>(
        Wvocab, Wih, Whh, bih, bhh, Wu, emb, answers, localf,
        WV, WG, BG, WU, Y, LFb);
    init_kernel<<<dim3(8, 4, 3), 256, 0, stream>>>(
        qvec, globalf, Wh, Wc, Wg2o, bg2o, HB, CF, OB);
    attnproj_kernel<<<dim3(49, 8), 256, 0, stream>>>(localf, Wattn, APb);
    loop_kernel<<<GRID_BLKS, 256, 0, stream>>>(
        Y, WG, BG, WU, bu, APb, LFb, localf, use_lfb,
        OB, HB, CF, AB, BAR + 0, BAR + 1);
    vocab_kernel<<<dim3(16, 79), 256, 0, stream>>>(OB + 32768, WV, bvocab, out);
}